// Round 10
// baseline (249.304 us; speedup 1.0000x reference)
//
#include <hip/hip_runtime.h>
#include <hip/hip_bf16.h>

typedef float f32x4 __attribute__((ext_vector_type(4)));
typedef __bf16 bf16x8 __attribute__((ext_vector_type(8)));
typedef __bf16 bf16x4 __attribute__((ext_vector_type(4)));
typedef unsigned short ushort4v __attribute__((ext_vector_type(4)));
typedef unsigned short ushort8v __attribute__((ext_vector_type(8)));

#define MFMA16(a, b, c) __builtin_amdgcn_mfma_f32_16x16x32_bf16((a), (b), (c), 0, 0, 0)

__device__ __forceinline__ unsigned short f2bf(float f) {
    union { float f; unsigned int u; } v; v.f = f;
    unsigned int r = (v.u + 0x7fffu + ((v.u >> 16) & 1u)) >> 16;  // RNE
    return (unsigned short)r;
}

// LDS-only barrier: flush this wave's LDS ops, then s_barrier (no vmcnt drain).
__device__ __forceinline__ void ldsbar() {
    asm volatile("s_waitcnt lgkmcnt(0)" ::: "memory");
    __builtin_amdgcn_s_barrier();
}

// ---------------------------------------------------------------------------
// Projection (unchanged from round 8 -- compile-time bounds, 56 us, correct).
// ---------------------------------------------------------------------------
__device__ __forceinline__ void stage_A(const float* __restrict__ E,
                                        unsigned short (*Al)[40], int row0, int k0, int tid)
{
    const int arow = tid >> 2;
    const int ak = (tid & 3) * 8;
    const float* ep = &E[(size_t)(row0 + arow) * 512 + k0 + ak];
    f32x4 v0 = *(const f32x4*)ep;
    f32x4 v1 = *(const f32x4*)(ep + 4);
    ushort8v u;
#pragma unroll
    for (int j = 0; j < 4; ++j) { u[j] = f2bf(v0[j]); u[4 + j] = f2bf(v1[j]); }
    *(ushort8v*)&Al[arow][ak] = u;
}

__device__ __forceinline__ void proj_qk_body(const float* __restrict__ E,
        const float* __restrict__ wq, const float* __restrict__ bq, unsigned short* __restrict__ Qb,
        const float* __restrict__ wk, const float* __restrict__ bk, unsigned short* __restrict__ Kb,
        unsigned short (*Al)[40], unsigned short (*Bl)[40], int bx)
{
    const int tid = threadIdx.x;
    const int w = tid >> 6, l = tid & 63, g = l >> 4, li = l & 15;
    const int wm = w >> 2, wn = w & 3;
    const int row0 = bx * 128;

    f32x4 acc[4][2];
#pragma unroll
    for (int mb = 0; mb < 4; ++mb)
#pragma unroll
        for (int nb = 0; nb < 2; ++nb) acc[mb][nb] = (f32x4)0.0f;

    for (int kt = 0; kt < 16; ++kt) {
        const int k0 = kt * 32;
        stage_A(E, Al, row0, k0, tid);
#pragma unroll
        for (int i = 0; i < 2; ++i) {
            const int kk = (tid >> 5) + 16 * i;
            const int cc = (tid & 31) * 4;
            const float* wsrc = (cc < 64) ? &wq[(size_t)(k0 + kk) * 64 + cc]
                                          : &wk[(size_t)(k0 + kk) * 64 + (cc - 64)];
            f32x4 v = *(const f32x4*)wsrc;
#pragma unroll
            for (int j = 0; j < 4; ++j) Bl[cc + j][kk] = f2bf(v[j]);
        }
        __syncthreads();

        bf16x8 af[4], bw[2];
#pragma unroll
        for (int mb = 0; mb < 4; ++mb) af[mb] = *(const bf16x8*)&Al[wm * 64 + mb * 16 + li][8 * g];
#pragma unroll
        for (int nb = 0; nb < 2; ++nb)
            bw[nb] = *(const bf16x8*)&Bl[wn * 32 + nb * 16 + li][8 * g];
#pragma unroll
        for (int mb = 0; mb < 4; ++mb)
#pragma unroll
            for (int nb = 0; nb < 2; ++nb) acc[mb][nb] = MFMA16(af[mb], bw[nb], acc[mb][nb]);
        __syncthreads();
    }

#pragma unroll
    for (int mb = 0; mb < 4; ++mb) {
#pragma unroll
        for (int nb = 0; nb < 2; ++nb) {
            const int coll = wn * 32 + nb * 16 + li;
            const int grow0 = row0 + wm * 64 + mb * 16 + 4 * g;
            if (coll < 64) {
                const float bb = bq[coll];
#pragma unroll
                for (int r = 0; r < 4; ++r)
                    Qb[(size_t)(grow0 + r) * 64 + coll] = f2bf((acc[mb][nb][r] + bb) * 0.125f);
            } else {
                const float bb = bk[coll - 64];
#pragma unroll
                for (int r = 0; r < 4; ++r)
                    Kb[(size_t)(grow0 + r) * 64 + (coll - 64)] = f2bf(acc[mb][nb][r] + bb);
            }
        }
    }
}

__device__ __forceinline__ void proj_v_body(const float* __restrict__ E,
        const float* __restrict__ wv, const float* __restrict__ bv, unsigned short* __restrict__ Vt,
        unsigned short (*Al)[40], unsigned short (*Bl)[40], int bx, int vy)
{
    const int tid = threadIdx.x;
    const int w = tid >> 6, l = tid & 63, g = l >> 4, li = l & 15;
    const int wm = w >> 2, wn = w & 3;
    const int row0 = bx * 128;
    const int c0v = vy * 256;

    f32x4 acc[4][4];
#pragma unroll
    for (int mb = 0; mb < 4; ++mb)
#pragma unroll
        for (int nb = 0; nb < 4; ++nb) acc[mb][nb] = (f32x4)0.0f;

    for (int kt = 0; kt < 16; ++kt) {
        const int k0 = kt * 32;
        stage_A(E, Al, row0, k0, tid);
#pragma unroll
        for (int i = 0; i < 4; ++i) {
            const int kk = (tid >> 6) + 8 * i;
            const int cc = (tid & 63) * 4;
            f32x4 v = *(const f32x4*)&wv[(size_t)(k0 + kk) * 512 + c0v + cc];
#pragma unroll
            for (int j = 0; j < 4; ++j) Bl[cc + j][kk] = f2bf(v[j]);
        }
        __syncthreads();

        bf16x8 af[4], bw[4];
#pragma unroll
        for (int mb = 0; mb < 4; ++mb) af[mb] = *(const bf16x8*)&Al[wm * 64 + mb * 16 + li][8 * g];
#pragma unroll
        for (int nb = 0; nb < 4; ++nb)
            bw[nb] = *(const bf16x8*)&Bl[wn * 64 + nb * 16 + li][8 * g];
#pragma unroll
        for (int mb = 0; mb < 4; ++mb)
#pragma unroll
            for (int nb = 0; nb < 4; ++nb) acc[mb][nb] = MFMA16(af[mb], bw[nb], acc[mb][nb]);
        __syncthreads();
    }

#pragma unroll
    for (int mb = 0; mb < 4; ++mb) {
#pragma unroll
        for (int nb = 0; nb < 4; ++nb) {
            const int col = c0v + wn * 64 + nb * 16 + li;
            const int grow0 = row0 + wm * 64 + mb * 16 + 4 * g;
            const float bb = bv[col];
            ushort4v u;
#pragma unroll
            for (int r = 0; r < 4; ++r) u[r] = f2bf(acc[mb][nb][r] + bb);
            const int bbatch = grow0 >> 12, n = grow0 & 4095;
            *(ushort4v*)(Vt + ((size_t)bbatch * 512 + col) * 4096 + n) = u;
        }
    }
}

__global__ __launch_bounds__(512) void proj_kernel(const float* __restrict__ E,
        const float* __restrict__ wq, const float* __restrict__ bq, unsigned short* __restrict__ Qb,
        const float* __restrict__ wk, const float* __restrict__ bk, unsigned short* __restrict__ Kb,
        const float* __restrict__ wv, const float* __restrict__ bv, unsigned short* __restrict__ Vt)
{
    __shared__ __align__(16) unsigned short Al[128][40];
    __shared__ __align__(16) unsigned short Bl[256][40];
    if (blockIdx.y == 0)
        proj_qk_body(E, wq, bq, Qb, wk, bk, Kb, Al, Bl, blockIdx.x);
    else
        proj_v_body(E, wv, bv, Vt, Al, Bl, blockIdx.x, blockIdx.y - 1);
}

// ---------------------------------------------------------------------------
// Causal flash attention, v10: UNIFORM-WORK blocks (hi/lo q-tile fusion with
// 33/32 kv split + intra-block partial merge), wave-local softmax (no cross-
// group exchange), ONE non-draining barrier per iteration, K/V global with
// full-iteration in-place prefetch.
// Grid 512 = 32 t x 4 b x 4 ch(128 cols). 8 waves = 2 groups x 4.
//  group0: q-tile hi=63-t, kv tiles [0,33)
//  group1: q-tile hi, kv tiles [33,64-t), then q-tile lo=t, kv [0,t]
// All blocks run exactly 33 iterations -> perfect balance on any scheduler.
// ---------------------------------------------------------------------------
__global__ __launch_bounds__(512) void attn_kernel(const unsigned short* __restrict__ Qb,
                                                   const unsigned short* __restrict__ Kb,
                                                   const unsigned short* __restrict__ Vt,
                                                   float* __restrict__ out)
{
    __shared__ __align__(16) unsigned short Pl[2][2][64][76];  // [grp][buf][q][kv+pad]
    __shared__ float scl[2][2][64];                            // [grp][buf][q] rescale
    __shared__ __align__(16) float O1buf[128][68];             // g1 hi O-partial [col][q+pad]
    __shared__ float m1l[64], l1l[64];                         // g1 hi m,l partials
    __shared__ float a0l[64], a1l[64], lfl[64], llo[64];       // merge factors / l sums

    const int tid = threadIdx.x;
    const int w = tid >> 6, lane = tid & 63, g = lane >> 4, li = lane & 15;
    const int grp = w >> 2, w4 = w & 3;
    const int bid = blockIdx.x;
    const int t = bid >> 4, b = (bid >> 2) & 3, ch = bid & 3;
    const int qhi = 63 - t, qlo = t;
    const int s = 31 - t;                 // g1 switch iteration
    const int qrow = 16 * w4 + li;        // lane-owned q row (tile-local)

    const unsigned short* qhp = Qb + ((size_t)(b * 4096 + qhi * 64 + qrow)) * 64 + 8 * g;
    const unsigned short* qlp = Qb + ((size_t)(b * 4096 + qlo * 64 + qrow)) * 64 + 8 * g;

    bf16x8 QA0, QA1;
    if (grp == 0 || s > 0) { QA0 = *(const bf16x8*)qhp; QA1 = *(const bf16x8*)(qhp + 32); }
    else                   { QA0 = *(const bf16x8*)qlp; QA1 = *(const bf16x8*)(qlp + 32); }

    float m_r = -INFINITY, l_r = 0.0f;
    f32x4 Of[4][2];
#pragma unroll
    for (int qb = 0; qb < 4; ++qb) { Of[qb][0] = (f32x4)0.0f; Of[qb][1] = (f32x4)0.0f; }

    const int cloc = w4 * 32 + li;        // local col within the 128-col chunk
    const int cglob = ch * 128 + cloc;
    const unsigned short* vbase = Vt + ((size_t)(b * 512 + cglob)) * 4096 + 8 * g;
    const unsigned short* kbase = Kb + ((size_t)(b * 4096 + li)) * 64 + 8 * g;

    // kv tile base (elements) at iteration j for this wave's group
    auto kvof = [&](int j) -> size_t {
        return (size_t)64 * (grp == 0 ? j : (j < s ? 33 + j : j - s));
    };

    // prologue: K/V for iteration 0
    bf16x8 KA[4][2], VB[2][2];
    {
        const size_t kv0 = kvof(0);
#pragma unroll
        for (int cb = 0; cb < 4; ++cb)
#pragma unroll
            for (int ks = 0; ks < 2; ++ks)
                KA[cb][ks] = *(const bf16x8*)(kbase + (kv0 + cb * 16) * 64 + ks * 32);
#pragma unroll
        for (int cf = 0; cf < 2; ++cf)
#pragma unroll
            for (int ks = 0; ks < 2; ++ks)
                VB[cf][ks] = *(const bf16x8*)(vbase + (size_t)cf * 16 * 4096 + kv0 + ks * 32);
    }

    for (int j = 0; j < 33; ++j) {
        const bool active = (grp == 0) || (j < 32);

        // group1 switches from hi to lo: stash hi partials, reset state
        if (grp == 1 && j == s) {
#pragma unroll
            for (int qb = 0; qb < 4; ++qb)
#pragma unroll
                for (int cf = 0; cf < 2; ++cf)
                    *(f32x4*)&O1buf[cloc + cf * 16][qb * 16 + 4 * g] = Of[qb][cf];
            if (g == 0) { m1l[qrow] = m_r; l1l[qrow] = l_r; }
#pragma unroll
            for (int qb = 0; qb < 4; ++qb) { Of[qb][0] = (f32x4)0.0f; Of[qb][1] = (f32x4)0.0f; }
            m_r = -INFINITY; l_r = 0.0f;
            QA0 = *(const bf16x8*)qlp; QA1 = *(const bf16x8*)(qlp + 32);
        }

        const int qcur = (grp == 0 || j < s) ? qhi : qlo;
        const size_t kv0 = kvof(j);
        const bool isdiag = (kv0 == (size_t)64 * qcur);

        // ---- S = (K Q^T)^T : kv lane-local (swapped MFMA) ----
        f32x4 S[4];
        if (active) {
            __builtin_amdgcn_s_setprio(1);
#pragma unroll
            for (int cb = 0; cb < 4; ++cb) {
                f32x4 sx = (f32x4)0.0f;
                sx = MFMA16(KA[cb][0], QA0, sx);
                sx = MFMA16(KA[cb][1], QA1, sx);
                S[cb] = sx;
            }
            __builtin_amdgcn_s_setprio(0);
        }
        // K prefetch for next iteration (full-iteration distance, in place)
        {
            const int jn = (j < 32) ? j + 1 : 32;
            const size_t kvn = kvof(jn);
#pragma unroll
            for (int cb = 0; cb < 4; ++cb)
#pragma unroll
                for (int ks = 0; ks < 2; ++ks)
                    KA[cb][ks] = *(const bf16x8*)(kbase + (kvn + cb * 16) * 64 + ks * 32);
        }

        if (active) {
            if (isdiag) {
#pragma unroll
                for (int cb = 0; cb < 4; ++cb)
#pragma unroll
                    for (int r = 0; r < 4; ++r)
                        if (cb * 16 + 4 * g + r > qrow) S[cb][r] = -1e30f;
            }
            // wave-local softmax over the full 64-kv row
            f32x4 m4 = S[0];
#pragma unroll
            for (int cb = 1; cb < 4; ++cb)
#pragma unroll
                for (int r = 0; r < 4; ++r) m4[r] = fmaxf(m4[r], S[cb][r]);
            float pm = fmaxf(fmaxf(m4[0], m4[1]), fmaxf(m4[2], m4[3]));
            pm = fmaxf(pm, __shfl_xor(pm, 16));
            pm = fmaxf(pm, __shfl_xor(pm, 32));
            const float mn = fmaxf(m_r, pm);
            const float sc = __expf(m_r - mn);
            m_r = mn;
            float rs = 0.0f;
#pragma unroll
            for (int cb = 0; cb < 4; ++cb) {
                bf16x4 pk;
#pragma unroll
                for (int r = 0; r < 4; ++r) {
                    const float pv = __expf(S[cb][r] - mn);
                    rs += pv;
                    pk[r] = (__bf16)pv;
                }
                *(bf16x4*)&Pl[grp][j & 1][qrow][cb * 16 + 4 * g] = pk;
            }
            rs += __shfl_xor(rs, 16);
            rs += __shfl_xor(rs, 32);
            l_r = l_r * sc + rs;
            if (g == 0) scl[grp][j & 1][qrow] = sc;
        }
        ldsbar();  // the single per-iteration barrier (LDS-only)

        if (active) {
            __builtin_amdgcn_s_setprio(1);
#pragma unroll
            for (int qb = 0; qb < 4; ++qb) {
                f32x4 scv = *(const f32x4*)&scl[grp][j & 1][qb * 16 + 4 * g];
                bf16x8 PA0 = *(const bf16x8*)&Pl[grp][j & 1][qb * 16 + li][8 * g];
                bf16x8 PA1 = *(const bf16x8*)&Pl[grp][j & 1][qb * 16 + li][32 + 8 * g];
#pragma unroll
                for (int cf = 0; cf < 2; ++cf) {
                    f32x4 o = Of[qb][cf];
#pragma unroll
                    for (int r = 0; r < 4; ++r) o[r] *= scv[r];
                    o = MFMA16(PA0, VB[cf][0], o);
                    o = MFMA16(PA1, VB[cf][1], o);
                    Of[qb][cf] = o;
                }
            }
            __builtin_amdgcn_s_setprio(0);
            // V prefetch for next iteration
            const int jn = (j < 32) ? j + 1 : 32;
            const size_t kvn = kvof(jn);
#pragma unroll
            for (int cf = 0; cf < 2; ++cf)
#pragma unroll
                for (int ks = 0; ks < 2; ++ks)
                    VB[cf][ks] = *(const bf16x8*)(vbase + (size_t)cf * 16 * 4096 + kvn + ks * 32);
        }
    }

    // ---- epilogue: merge hi partials (g0 + g1's stash), write out ----
    ldsbar();
    if (g == 0) {
        if (grp == 0) {
            const float m1 = m1l[qrow], l1v = l1l[qrow];
            const float mF = fmaxf(m_r, m1);
            const float a0 = __expf(m_r - mF);
            const float a1 = __expf(m1 - mF);
            a0l[qrow] = a0; a1l[qrow] = a1;
            lfl[qrow] = a0 * l_r + a1 * l1v;
        } else {
            llo[qrow] = l_r;
        }
    }
    ldsbar();

    const int q0 = (grp == 0 ? qhi : qlo) * 64;
    float* obase = out + (size_t)(b * 4096 + q0 + 4 * g) * 512 + cglob;
    if (grp == 0) {
#pragma unroll
        for (int qb = 0; qb < 4; ++qb) {
            f32x4 a0v = *(const f32x4*)&a0l[qb * 16 + 4 * g];
            f32x4 a1v = *(const f32x4*)&a1l[qb * 16 + 4 * g];
            f32x4 lv  = *(const f32x4*)&lfl[qb * 16 + 4 * g];
#pragma unroll
            for (int cf = 0; cf < 2; ++cf) {
                f32x4 o1 = *(const f32x4*)&O1buf[cloc + cf * 16][qb * 16 + 4 * g];
#pragma unroll
                for (int r = 0; r < 4; ++r)
                    obase[(size_t)(qb * 16 + r) * 512 + cf * 16] =
                        (a0v[r] * Of[qb][cf][r] + a1v[r] * o1[r]) / lv[r];
            }
        }
    } else {
#pragma unroll
        for (int qb = 0; qb < 4; ++qb) {
            f32x4 lv = *(const f32x4*)&llo[qb * 16 + 4 * g];
#pragma unroll
            for (int cf = 0; cf < 2; ++cf)
#pragma unroll
                for (int r = 0; r < 4; ++r)
                    obase[(size_t)(qb * 16 + r) * 512 + cf * 16] = Of[qb][cf][r] / lv[r];
        }
    }
}

// ---------------------------------------------------------------------------
extern "C" void kernel_launch(void* const* d_in, const int* in_sizes, int n_in,
                              void* d_out, int out_size, void* d_ws, size_t ws_size,
                              hipStream_t stream)
{
    (void)in_sizes; (void)n_in; (void)out_size; (void)ws_size;
    const float* E  = (const float*)d_in[0];
    const float* wq = (const float*)d_in[2];
    const float* bq = (const float*)d_in[3];
    const float* wk = (const float*)d_in[4];
    const float* bk = (const float*)d_in[5];
    const float* wv = (const float*)d_in[6];
    const float* bv = (const float*)d_in[7];

    const size_t qk_elems = (size_t)4 * 4096 * 64;

    unsigned short* Qb = (unsigned short*)d_ws;                 // [4][4096][64] bf16 (x0.125)
    unsigned short* Kb = Qb + qk_elems;                         // [4][4096][64] bf16
    unsigned short* Vt = Kb + qk_elems;                         // [4][512][4096] bf16 (transposed)
    float* out = (float*)d_out;

    proj_kernel<<<dim3(128, 3), 512, 0, stream>>>(E, wq, bq, Qb, wk, bk, Kb, wv, bv, Vt);
    attn_kernel<<<dim3(512), 512, 0, stream>>>(Qb, Kb, Vt, out);
}

// Round 11
// 185.781 us; speedup vs baseline: 1.3419x; 1.3419x over previous
//
#include <hip/hip_runtime.h>
#include <hip/hip_bf16.h>

typedef float f32x4 __attribute__((ext_vector_type(4)));
typedef __bf16 bf16x8 __attribute__((ext_vector_type(8)));
typedef __bf16 bf16x4 __attribute__((ext_vector_type(4)));
typedef unsigned short ushort4v __attribute__((ext_vector_type(4)));
typedef unsigned short ushort8v __attribute__((ext_vector_type(8)));

#define MFMA16(a, b, c) __builtin_amdgcn_mfma_f32_16x16x32_bf16((a), (b), (c), 0, 0, 0)

__device__ __forceinline__ unsigned short f2bf(float f) {
    union { float f; unsigned int u; } v; v.f = f;
    unsigned int r = (v.u + 0x7fffu + ((v.u >> 16) & 1u)) >> 16;  // RNE
    return (unsigned short)r;
}
__device__ __forceinline__ int imin(int a, int b) { return a < b ? a : b; }

// LDS-only barrier: flush this wave's LDS ops, then s_barrier (no vmcnt drain).
__device__ __forceinline__ void ldsbar() {
    asm volatile("s_waitcnt lgkmcnt(0)" ::: "memory");
    __builtin_amdgcn_s_barrier();
}

// ---------------------------------------------------------------------------
// Projection (round-8 version: compile-time bounds, ~56 us measured).
// ---------------------------------------------------------------------------
__device__ __forceinline__ void stage_A(const float* __restrict__ E,
                                        unsigned short (*Al)[40], int row0, int k0, int tid)
{
    const int arow = tid >> 2;
    const int ak = (tid & 3) * 8;
    const float* ep = &E[(size_t)(row0 + arow) * 512 + k0 + ak];
    f32x4 v0 = *(const f32x4*)ep;
    f32x4 v1 = *(const f32x4*)(ep + 4);
    ushort8v u;
#pragma unroll
    for (int j = 0; j < 4; ++j) { u[j] = f2bf(v0[j]); u[4 + j] = f2bf(v1[j]); }
    *(ushort8v*)&Al[arow][ak] = u;
}

__device__ __forceinline__ void proj_qk_body(const float* __restrict__ E,
        const float* __restrict__ wq, const float* __restrict__ bq, unsigned short* __restrict__ Qb,
        const float* __restrict__ wk, const float* __restrict__ bk, unsigned short* __restrict__ Kb,
        unsigned short (*Al)[40], unsigned short (*Bl)[40], int bx)
{
    const int tid = threadIdx.x;
    const int w = tid >> 6, l = tid & 63, g = l >> 4, li = l & 15;
    const int wm = w >> 2, wn = w & 3;
    const int row0 = bx * 128;

    f32x4 acc[4][2];
#pragma unroll
    for (int mb = 0; mb < 4; ++mb)
#pragma unroll
        for (int nb = 0; nb < 2; ++nb) acc[mb][nb] = (f32x4)0.0f;

    for (int kt = 0; kt < 16; ++kt) {
        const int k0 = kt * 32;
        stage_A(E, Al, row0, k0, tid);
#pragma unroll
        for (int i = 0; i < 2; ++i) {
            const int kk = (tid >> 5) + 16 * i;
            const int cc = (tid & 31) * 4;
            const float* wsrc = (cc < 64) ? &wq[(size_t)(k0 + kk) * 64 + cc]
                                          : &wk[(size_t)(k0 + kk) * 64 + (cc - 64)];
            f32x4 v = *(const f32x4*)wsrc;
#pragma unroll
            for (int j = 0; j < 4; ++j) Bl[cc + j][kk] = f2bf(v[j]);
        }
        __syncthreads();

        bf16x8 af[4], bw[2];
#pragma unroll
        for (int mb = 0; mb < 4; ++mb) af[mb] = *(const bf16x8*)&Al[wm * 64 + mb * 16 + li][8 * g];
#pragma unroll
        for (int nb = 0; nb < 2; ++nb)
            bw[nb] = *(const bf16x8*)&Bl[wn * 32 + nb * 16 + li][8 * g];
#pragma unroll
        for (int mb = 0; mb < 4; ++mb)
#pragma unroll
            for (int nb = 0; nb < 2; ++nb) acc[mb][nb] = MFMA16(af[mb], bw[nb], acc[mb][nb]);
        __syncthreads();
    }

#pragma unroll
    for (int mb = 0; mb < 4; ++mb) {
#pragma unroll
        for (int nb = 0; nb < 2; ++nb) {
            const int coll = wn * 32 + nb * 16 + li;
            const int grow0 = row0 + wm * 64 + mb * 16 + 4 * g;
            if (coll < 64) {
                const float bb = bq[coll];
#pragma unroll
                for (int r = 0; r < 4; ++r)
                    Qb[(size_t)(grow0 + r) * 64 + coll] = f2bf((acc[mb][nb][r] + bb) * 0.125f);
            } else {
                const float bb = bk[coll - 64];
#pragma unroll
                for (int r = 0; r < 4; ++r)
                    Kb[(size_t)(grow0 + r) * 64 + (coll - 64)] = f2bf(acc[mb][nb][r] + bb);
            }
        }
    }
}

__device__ __forceinline__ void proj_v_body(const float* __restrict__ E,
        const float* __restrict__ wv, const float* __restrict__ bv, unsigned short* __restrict__ Vt,
        unsigned short (*Al)[40], unsigned short (*Bl)[40], int bx, int vy)
{
    const int tid = threadIdx.x;
    const int w = tid >> 6, l = tid & 63, g = l >> 4, li = l & 15;
    const int wm = w >> 2, wn = w & 3;
    const int row0 = bx * 128;
    const int c0v = vy * 256;

    f32x4 acc[4][4];
#pragma unroll
    for (int mb = 0; mb < 4; ++mb)
#pragma unroll
        for (int nb = 0; nb < 4; ++nb) acc[mb][nb] = (f32x4)0.0f;

    for (int kt = 0; kt < 16; ++kt) {
        const int k0 = kt * 32;
        stage_A(E, Al, row0, k0, tid);
#pragma unroll
        for (int i = 0; i < 4; ++i) {
            const int kk = (tid >> 6) + 8 * i;
            const int cc = (tid & 63) * 4;
            f32x4 v = *(const f32x4*)&wv[(size_t)(k0 + kk) * 512 + c0v + cc];
#pragma unroll
            for (int j = 0; j < 4; ++j) Bl[cc + j][kk] = f2bf(v[j]);
        }
        __syncthreads();

        bf16x8 af[4], bw[4];
#pragma unroll
        for (int mb = 0; mb < 4; ++mb) af[mb] = *(const bf16x8*)&Al[wm * 64 + mb * 16 + li][8 * g];
#pragma unroll
        for (int nb = 0; nb < 4; ++nb)
            bw[nb] = *(const bf16x8*)&Bl[wn * 64 + nb * 16 + li][8 * g];
#pragma unroll
        for (int mb = 0; mb < 4; ++mb)
#pragma unroll
            for (int nb = 0; nb < 4; ++nb) acc[mb][nb] = MFMA16(af[mb], bw[nb], acc[mb][nb]);
        __syncthreads();
    }

#pragma unroll
    for (int mb = 0; mb < 4; ++mb) {
#pragma unroll
        for (int nb = 0; nb < 4; ++nb) {
            const int col = c0v + wn * 64 + nb * 16 + li;
            const int grow0 = row0 + wm * 64 + mb * 16 + 4 * g;
            const float bb = bv[col];
            ushort4v u;
#pragma unroll
            for (int r = 0; r < 4; ++r) u[r] = f2bf(acc[mb][nb][r] + bb);
            const int bbatch = grow0 >> 12, n = grow0 & 4095;
            *(ushort4v*)(Vt + ((size_t)bbatch * 512 + col) * 4096 + n) = u;
        }
    }
}

__global__ __launch_bounds__(512) void proj_kernel(const float* __restrict__ E,
        const float* __restrict__ wq, const float* __restrict__ bq, unsigned short* __restrict__ Qb,
        const float* __restrict__ wk, const float* __restrict__ bk, unsigned short* __restrict__ Kb,
        const float* __restrict__ wv, const float* __restrict__ bv, unsigned short* __restrict__ Vt)
{
    __shared__ __align__(16) unsigned short Al[128][40];
    __shared__ __align__(16) unsigned short Bl[256][40];
    if (blockIdx.y == 0)
        proj_qk_body(E, wq, bq, Qb, wk, bk, Kb, Al, Bl, blockIdx.x);
    else
        proj_v_body(E, wv, bv, Vt, Al, Bl, blockIdx.x, blockIdx.y - 1);
}

// ---------------------------------------------------------------------------
// Causal flash attention, v11 = v6 (best measured: 127 us) + Pl pad 72->76
// (v10-proven bank-conflict fix: 5.3M -> 65K conflict cycles).
// K staged in LDS (XOR-swizzled, double-buffered, coalesced row loads --
// every K-from-global variant regressed); swapped QK^T (kv lane-local
// softmax); dual-stream 2x64 kv/iter; V reg loads; non-draining barriers;
// qt-paired dispatch; setprio on MFMA clusters.
// ---------------------------------------------------------------------------
__global__ __launch_bounds__(512) void attn_kernel(const unsigned short* __restrict__ Qb,
                                                   const unsigned short* __restrict__ Kb,
                                                   const unsigned short* __restrict__ Vt,
                                                   float* __restrict__ out)
{
    __shared__ __align__(16) unsigned short Kl[2][2][64][64];  // [buf][tile][kv][d], chunk^row swizzle
    __shared__ __align__(16) unsigned short Pl[2][64][76];     // [grp][q][kv] (+12 pad: conflict-free)
    __shared__ float pm2[2][64];
    __shared__ float rs2[64];
    __shared__ float scl_l[64];
    __shared__ float lsum_l[64];

    const int tid = threadIdx.x;
    const int w = tid >> 6, l = tid & 63, g = l >> 4, li = l & 15;
    const int grp = w >> 2, wq4 = w & 3;
    const int bid = blockIdx.x;
    const int t = bid >> 3, b = (bid >> 1) & 3, ch = bid & 1;
    const int qt = (t < 32) ? (63 - t) : (t - 32);
    const int q0 = qt * 64;
    const int niter = (qt >> 1) + 1;
    const int qrow = 16 * wq4 + li;  // tile-local q row owned by this lane in phase A

    const unsigned short* qptr = Qb + ((size_t)(b * 4096 + q0 + qrow)) * 64 + 8 * g;
    const bf16x8 QA0 = *(const bf16x8*)qptr;
    const bf16x8 QA1 = *(const bf16x8*)(qptr + 32);

    float m_r = -INFINITY, l_r = 0.0f;

    f32x4 Of[4][2];
#pragma unroll
    for (int qb = 0; qb < 4; ++qb) { Of[qb][0] = (f32x4)0.0f; Of[qb][1] = (f32x4)0.0f; }

    const int cglob = ch * 256 + w * 32 + li;
    const unsigned short* vb2 = Vt + ((size_t)(b * 512 + cglob)) * 4096 + 8 * g;

    const int krow = tid >> 3, kch = tid & 7;
    const unsigned short* kgb = Kb + ((size_t)(b * 4096 + krow)) * 64 + kch * 8;
    const int kslot = (kch ^ (krow & 7)) * 8;

    {   // prologue: stage kv-pair 0 into buf 0
        ushort8v v0 = *(const ushort8v*)(kgb);
        ushort8v v1 = *(const ushort8v*)(kgb + (size_t)imin(1, qt) * 4096);
        *(ushort8v*)&Kl[0][0][krow][kslot] = v0;
        *(ushort8v*)&Kl[0][1][krow][kslot] = v1;
    }
    ldsbar();

    for (int k = 0; k < niter; ++k) {
        const int buf = k & 1;
        const int tA = 2 * k, tB = 2 * k + 1;
        const bool actB = (tB <= qt);
        const int myt = grp ? tB : tA;
        const bool act = grp ? actB : true;

        // next-pair K global loads (stay in flight across barrier 1)
        ushort8v kn0, kn1;
        const bool havenext = (k + 1 < niter);
        if (havenext) {
            kn0 = *(const ushort8v*)(kgb + (size_t)imin(2 * k + 2, qt) * 4096);
            kn1 = *(const ushort8v*)(kgb + (size_t)imin(2 * k + 3, qt) * 4096);
        }
        // this iteration's V loads (consumed in phase B)
        const size_t kvA = (size_t)tA * 64;
        const size_t kvB = (size_t)imin(tB, qt) * 64;
        bf16x8 VA[2][2], VBt[2][2];
#pragma unroll
        for (int cf = 0; cf < 2; ++cf)
#pragma unroll
            for (int ks = 0; ks < 2; ++ks) {
                VA[cf][ks] = *(const bf16x8*)(vb2 + (size_t)cf * 16 * 4096 + kvA + ks * 32);
                VBt[cf][ks] = *(const bf16x8*)(vb2 + (size_t)cf * 16 * 4096 + kvB + ks * 32);
            }

        // ---- phase A (swapped): S^T[kv][q], kv lane-local ----
        f32x4 S[4];
        float pm;
        if (act) {
            const unsigned short(*Kt)[64] = Kl[buf][grp];
            __builtin_amdgcn_s_setprio(1);
#pragma unroll
            for (int cb = 0; cb < 4; ++cb) {
                const int row = cb * 16 + li;
                bf16x8 K0 = *(const bf16x8*)&Kt[row][((g) ^ (row & 7)) * 8];
                bf16x8 K1 = *(const bf16x8*)&Kt[row][((4 + g) ^ (row & 7)) * 8];
                f32x4 s = (f32x4)0.0f;
                s = MFMA16(K0, QA0, s);   // A = K, B = Q  ->  D = S^T
                s = MFMA16(K1, QA1, s);
                S[cb] = s;
            }
            __builtin_amdgcn_s_setprio(0);
            if (myt == qt) {  // diagonal tile: mask kv > q
#pragma unroll
                for (int cb = 0; cb < 4; ++cb)
#pragma unroll
                    for (int r = 0; r < 4; ++r)
                        if (cb * 16 + 4 * g + r > qrow) S[cb][r] = -1e30f;
            }
            // in-lane max over this lane's 16 kv values
            f32x4 m4 = S[0];
#pragma unroll
            for (int cb = 1; cb < 4; ++cb)
#pragma unroll
                for (int r = 0; r < 4; ++r) m4[r] = fmaxf(m4[r], S[cb][r]);
            pm = fmaxf(fmaxf(m4[0], m4[1]), fmaxf(m4[2], m4[3]));
            pm = fmaxf(pm, __shfl_xor(pm, 16));
            pm = fmaxf(pm, __shfl_xor(pm, 32));
        } else {
            pm = -INFINITY;
        }
        if (g == 0) pm2[grp][qrow] = pm;
        ldsbar();  // barrier 1 (LDS-only)

        const float mn = fmaxf(m_r, fmaxf(pm2[0][qrow], pm2[1][qrow]));
        const float sc = __expf(m_r - mn);
        m_r = mn;
        if (grp == 0 && g == 0) scl_l[qrow] = sc;

        float rs = 0.0f;
        if (act) {
#pragma unroll
            for (int cb = 0; cb < 4; ++cb) {
                bf16x4 pk;
#pragma unroll
                for (int r = 0; r < 4; ++r) {
                    const float pv = __expf(S[cb][r] - mn);
                    rs += pv;
                    pk[r] = (__bf16)pv;
                }
                *(bf16x4*)&Pl[grp][qrow][cb * 16 + 4 * g] = pk;  // ds_write_b64
            }
            rs += __shfl_xor(rs, 16);
            rs += __shfl_xor(rs, 32);
        }
        if (grp == 1 && g == 0) rs2[qrow] = rs;

        // land next K pair into the other buffer
        if (havenext) {
            *(ushort8v*)&Kl[buf ^ 1][0][krow][kslot] = kn0;
            *(ushort8v*)&Kl[buf ^ 1][1][krow][kslot] = kn1;
        }
        ldsbar();  // barrier 2 (LDS-only)

        if (grp == 0) l_r = l_r * sc + rs + rs2[qrow];

        // ---- phase B: PV ----
        __builtin_amdgcn_s_setprio(1);
#pragma unroll
        for (int qb = 0; qb < 4; ++qb) {
            f32x4 scv = *(const f32x4*)&scl_l[qb * 16 + 4 * g];
            bf16x8 PA0 = *(const bf16x8*)&Pl[0][qb * 16 + li][8 * g];
            bf16x8 PA1 = *(const bf16x8*)&Pl[0][qb * 16 + li][32 + 8 * g];
#pragma unroll
            for (int cf = 0; cf < 2; ++cf) {
                f32x4 o = Of[qb][cf];
#pragma unroll
                for (int r = 0; r < 4; ++r) o[r] *= scv[r];
                o = MFMA16(PA0, VA[cf][0], o);
                o = MFMA16(PA1, VA[cf][1], o);
                Of[qb][cf] = o;
            }
            if (actB) {
                bf16x8 PB0 = *(const bf16x8*)&Pl[1][qb * 16 + li][8 * g];
                bf16x8 PB1 = *(const bf16x8*)&Pl[1][qb * 16 + li][32 + 8 * g];
#pragma unroll
                for (int cf = 0; cf < 2; ++cf) {
                    f32x4 o = Of[qb][cf];
                    o = MFMA16(PB0, VBt[cf][0], o);
                    o = MFMA16(PB1, VBt[cf][1], o);
                    Of[qb][cf] = o;
                }
            }
        }
        __builtin_amdgcn_s_setprio(0);
    }

    if (grp == 0 && g == 0) lsum_l[qrow] = l_r;
    ldsbar();

    float* obase = out + (size_t)(b * 4096 + q0 + 4 * g) * 512 + cglob;
#pragma unroll
    for (int qb = 0; qb < 4; ++qb) {
        f32x4 lv = *(const f32x4*)&lsum_l[qb * 16 + 4 * g];
#pragma unroll
        for (int cf = 0; cf < 2; ++cf)
#pragma unroll
            for (int r = 0; r < 4; ++r)
                obase[(size_t)(qb * 16 + r) * 512 + cf * 16] = Of[qb][cf][r] / lv[r];
    }
}

// ---------------------------------------------------------------------------
extern "C" void kernel_launch(void* const* d_in, const int* in_sizes, int n_in,
                              void* d_out, int out_size, void* d_ws, size_t ws_size,
                              hipStream_t stream)
{
    (void)in_sizes; (void)n_in; (void)out_size; (void)ws_size;
    const float* E  = (const float*)d_in[0];
    const float* wq = (const float*)d_in[2];
    const float* bq = (const float*)d_in[3];
    const float* wk = (const float*)d_in[4];
    const float* bk = (const float*)d_in[5];
    const float* wv = (const float*)d_in[6];
    const float* bv = (const float*)d_in[7];

    const size_t qk_elems = (size_t)4 * 4096 * 64;

    unsigned short* Qb = (unsigned short*)d_ws;                 // [4][4096][64] bf16 (x0.125)
    unsigned short* Kb = Qb + qk_elems;                         // [4][4096][64] bf16
    unsigned short* Vt = Kb + qk_elems;                         // [4][512][4096] bf16 (transposed)
    float* out = (float*)d_out;

    proj_kernel<<<dim3(128, 3), 512, 0, stream>>>(E, wq, bq, Qb, wk, bk, Kb, wv, bv, Vt);
    attn_kernel<<<dim3(512), 512, 0, stream>>>(Qb, Kb, Vt, out);
}

// Round 12
// 156.979 us; speedup vs baseline: 1.5881x; 1.1835x over previous
//
#include <hip/hip_runtime.h>
#include <hip/hip_bf16.h>

typedef float f32x4 __attribute__((ext_vector_type(4)));
typedef __bf16 bf16x8 __attribute__((ext_vector_type(8)));
typedef __bf16 bf16x4 __attribute__((ext_vector_type(4)));
typedef unsigned short ushort4v __attribute__((ext_vector_type(4)));
typedef unsigned short ushort8v __attribute__((ext_vector_type(8)));

#define MFMA16(a, b, c) __builtin_amdgcn_mfma_f32_16x16x32_bf16((a), (b), (c), 0, 0, 0)

__device__ __forceinline__ unsigned short f2bf(float f) {
    union { float f; unsigned int u; } v; v.f = f;
    unsigned int r = (v.u + 0x7fffu + ((v.u >> 16) & 1u)) >> 16;  // RNE
    return (unsigned short)r;
}
__device__ __forceinline__ int imin(int a, int b) { return a < b ? a : b; }

// LDS-only barrier: flush this wave's LDS ops, then s_barrier (no vmcnt drain).
__device__ __forceinline__ void ldsbar() {
    asm volatile("s_waitcnt lgkmcnt(0)" ::: "memory");
    __builtin_amdgcn_s_barrier();
}

// ---------------------------------------------------------------------------
// Projection (round-8 version, ~56 us measured, unchanged).
// ---------------------------------------------------------------------------
__device__ __forceinline__ void stage_A(const float* __restrict__ E,
                                        unsigned short (*Al)[40], int row0, int k0, int tid)
{
    const int arow = tid >> 2;
    const int ak = (tid & 3) * 8;
    const float* ep = &E[(size_t)(row0 + arow) * 512 + k0 + ak];
    f32x4 v0 = *(const f32x4*)ep;
    f32x4 v1 = *(const f32x4*)(ep + 4);
    ushort8v u;
#pragma unroll
    for (int j = 0; j < 4; ++j) { u[j] = f2bf(v0[j]); u[4 + j] = f2bf(v1[j]); }
    *(ushort8v*)&Al[arow][ak] = u;
}

__device__ __forceinline__ void proj_qk_body(const float* __restrict__ E,
        const float* __restrict__ wq, const float* __restrict__ bq, unsigned short* __restrict__ Qb,
        const float* __restrict__ wk, const float* __restrict__ bk, unsigned short* __restrict__ Kb,
        unsigned short (*Al)[40], unsigned short (*Bl)[40], int bx)
{
    const int tid = threadIdx.x;
    const int w = tid >> 6, l = tid & 63, g = l >> 4, li = l & 15;
    const int wm = w >> 2, wn = w & 3;
    const int row0 = bx * 128;

    f32x4 acc[4][2];
#pragma unroll
    for (int mb = 0; mb < 4; ++mb)
#pragma unroll
        for (int nb = 0; nb < 2; ++nb) acc[mb][nb] = (f32x4)0.0f;

    for (int kt = 0; kt < 16; ++kt) {
        const int k0 = kt * 32;
        stage_A(E, Al, row0, k0, tid);
#pragma unroll
        for (int i = 0; i < 2; ++i) {
            const int kk = (tid >> 5) + 16 * i;
            const int cc = (tid & 31) * 4;
            const float* wsrc = (cc < 64) ? &wq[(size_t)(k0 + kk) * 64 + cc]
                                          : &wk[(size_t)(k0 + kk) * 64 + (cc - 64)];
            f32x4 v = *(const f32x4*)wsrc;
#pragma unroll
            for (int j = 0; j < 4; ++j) Bl[cc + j][kk] = f2bf(v[j]);
        }
        __syncthreads();

        bf16x8 af[4], bw[2];
#pragma unroll
        for (int mb = 0; mb < 4; ++mb) af[mb] = *(const bf16x8*)&Al[wm * 64 + mb * 16 + li][8 * g];
#pragma unroll
        for (int nb = 0; nb < 2; ++nb)
            bw[nb] = *(const bf16x8*)&Bl[wn * 32 + nb * 16 + li][8 * g];
#pragma unroll
        for (int mb = 0; mb < 4; ++mb)
#pragma unroll
            for (int nb = 0; nb < 2; ++nb) acc[mb][nb] = MFMA16(af[mb], bw[nb], acc[mb][nb]);
        __syncthreads();
    }

#pragma unroll
    for (int mb = 0; mb < 4; ++mb) {
#pragma unroll
        for (int nb = 0; nb < 2; ++nb) {
            const int coll = wn * 32 + nb * 16 + li;
            const int grow0 = row0 + wm * 64 + mb * 16 + 4 * g;
            if (coll < 64) {
                const float bb = bq[coll];
#pragma unroll
                for (int r = 0; r < 4; ++r)
                    Qb[(size_t)(grow0 + r) * 64 + coll] = f2bf((acc[mb][nb][r] + bb) * 0.125f);
            } else {
                const float bb = bk[coll - 64];
#pragma unroll
                for (int r = 0; r < 4; ++r)
                    Kb[(size_t)(grow0 + r) * 64 + (coll - 64)] = f2bf(acc[mb][nb][r] + bb);
            }
        }
    }
}

__device__ __forceinline__ void proj_v_body(const float* __restrict__ E,
        const float* __restrict__ wv, const float* __restrict__ bv, unsigned short* __restrict__ Vt,
        unsigned short (*Al)[40], unsigned short (*Bl)[40], int bx, int vy)
{
    const int tid = threadIdx.x;
    const int w = tid >> 6, l = tid & 63, g = l >> 4, li = l & 15;
    const int wm = w >> 2, wn = w & 3;
    const int row0 = bx * 128;
    const int c0v = vy * 256;

    f32x4 acc[4][4];
#pragma unroll
    for (int mb = 0; mb < 4; ++mb)
#pragma unroll
        for (int nb = 0; nb < 4; ++nb) acc[mb][nb] = (f32x4)0.0f;

    for (int kt = 0; kt < 16; ++kt) {
        const int k0 = kt * 32;
        stage_A(E, Al, row0, k0, tid);
#pragma unroll
        for (int i = 0; i < 4; ++i) {
            const int kk = (tid >> 6) + 8 * i;
            const int cc = (tid & 63) * 4;
            f32x4 v = *(const f32x4*)&wv[(size_t)(k0 + kk) * 512 + c0v + cc];
#pragma unroll
            for (int j = 0; j < 4; ++j) Bl[cc + j][kk] = f2bf(v[j]);
        }
        __syncthreads();

        bf16x8 af[4], bw[4];
#pragma unroll
        for (int mb = 0; mb < 4; ++mb) af[mb] = *(const bf16x8*)&Al[wm * 64 + mb * 16 + li][8 * g];
#pragma unroll
        for (int nb = 0; nb < 4; ++nb)
            bw[nb] = *(const bf16x8*)&Bl[wn * 64 + nb * 16 + li][8 * g];
#pragma unroll
        for (int mb = 0; mb < 4; ++mb)
#pragma unroll
            for (int nb = 0; nb < 4; ++nb) acc[mb][nb] = MFMA16(af[mb], bw[nb], acc[mb][nb]);
        __syncthreads();
    }

#pragma unroll
    for (int mb = 0; mb < 4; ++mb) {
#pragma unroll
        for (int nb = 0; nb < 4; ++nb) {
            const int col = c0v + wn * 64 + nb * 16 + li;
            const int grow0 = row0 + wm * 64 + mb * 16 + 4 * g;
            const float bb = bv[col];
            ushort4v u;
#pragma unroll
            for (int r = 0; r < 4; ++r) u[r] = f2bf(acc[mb][nb][r] + bb);
            const int bbatch = grow0 >> 12, n = grow0 & 4095;
            *(ushort4v*)(Vt + ((size_t)bbatch * 512 + col) * 4096 + n) = u;
        }
    }
}

__global__ __launch_bounds__(512) void proj_kernel(const float* __restrict__ E,
        const float* __restrict__ wq, const float* __restrict__ bq, unsigned short* __restrict__ Qb,
        const float* __restrict__ wk, const float* __restrict__ bk, unsigned short* __restrict__ Kb,
        const float* __restrict__ wv, const float* __restrict__ bv, unsigned short* __restrict__ Vt)
{
    __shared__ __align__(16) unsigned short Al[128][40];
    __shared__ __align__(16) unsigned short Bl[256][40];
    if (blockIdx.y == 0)
        proj_qk_body(E, wq, bq, Qb, wk, bk, Kb, Al, Bl, blockIdx.x);
    else
        proj_v_body(E, wv, bv, Vt, Al, Bl, blockIdx.x, blockIdx.y - 1);
}

// ---------------------------------------------------------------------------
// Causal flash attention, v12: 4-wave blocks (64q x 128c), single 64-kv tile
// per iteration, WAVE-LOCAL softmax (wave w owns q-block w: own m/l, zero
// cross-wave exchange), ONE non-draining barrier per iteration, 4 blocks/CU
// co-resident (independent latency chains). K LDS XOR-staged double-buffered;
// V reg loads; Pl/scl double-buffered; [76] pad (0 conflicts, v11-proven).
// Grid 1024 = 64 x 4 b x 4 ch; qt = tau(x) so the 4 co-resident blocks of a
// CU sum to exactly 130 iterations under round-robin dispatch.
// ---------------------------------------------------------------------------
__global__ __launch_bounds__(256) void attn_kernel(const unsigned short* __restrict__ Qb,
                                                   const unsigned short* __restrict__ Kb,
                                                   const unsigned short* __restrict__ Vt,
                                                   float* __restrict__ out)
{
    __shared__ __align__(16) unsigned short Kl[2][64][64];  // [buf][kv][d], chunk^row swizzle
    __shared__ __align__(16) unsigned short Pl[2][64][76];  // [buf][q][kv+pad]
    __shared__ float scl[2][64];
    __shared__ float lsum_l[64];

    const int tid = threadIdx.x;
    const int w = tid >> 6, lane = tid & 63, g = lane >> 4, li = lane & 15;
    const int bid = blockIdx.x;
    const int x = bid >> 4, b = (bid >> 2) & 3, ch = bid & 3;
    const int k4 = x >> 4, r4 = x & 15;
    // tau: co-resident {r,r+16,r+32,r+48} -> qts {r, 63-r, 16+r, 47-r}, sum 126
    const int qt = (k4 == 0) ? r4 : (k4 == 1) ? (63 - r4) : (k4 == 2) ? (16 + r4) : (47 - r4);
    const int q0 = qt * 64;
    const int niter = qt + 1;
    const int qrow = 16 * w + li;   // this wave's q rows (tile-local)

    const unsigned short* qptr = Qb + ((size_t)(b * 4096 + q0 + qrow)) * 64 + 8 * g;
    const bf16x8 QA0 = *(const bf16x8*)qptr;
    const bf16x8 QA1 = *(const bf16x8*)(qptr + 32);

    float m_r = -INFINITY, l_r = 0.0f;
    f32x4 Of[4][2];
#pragma unroll
    for (int qb = 0; qb < 4; ++qb) { Of[qb][0] = (f32x4)0.0f; Of[qb][1] = (f32x4)0.0f; }

    const int cglob = ch * 128 + w * 32 + li;
    const unsigned short* vbase = Vt + ((size_t)(b * 512 + cglob)) * 4096 + 8 * g;

    // K staging: 256 threads, each stages rows krow and krow+32, chunk kch
    const int krow = tid >> 3, kch = tid & 7;
    const unsigned short* kgb = Kb + ((size_t)(b * 4096 + krow)) * 64 + kch * 8;
    const int kslot = (kch ^ (krow & 7)) * 8;   // same for krow+32 ((krow+32)&7 == krow&7)

    {   // prologue: stage tile 0 into buf 0
        ushort8v v0 = *(const ushort8v*)(kgb);
        ushort8v v1 = *(const ushort8v*)(kgb + 32 * 64);
        *(ushort8v*)&Kl[0][krow][kslot] = v0;
        *(ushort8v*)&Kl[0][krow + 32][kslot] = v1;
    }
    ldsbar();

    for (int j = 0; j < niter; ++j) {
        const int buf = j & 1;
        const size_t kv0 = (size_t)j * 64;
        const bool havenext = (j + 1 < niter);

        // next-tile K global loads (land into other buf before the barrier)
        const size_t kvn = (size_t)imin(j + 1, qt) * 4096;  // element offset of next tile
        ushort8v kn0 = *(const ushort8v*)(kgb + kvn);
        ushort8v kn1 = *(const ushort8v*)(kgb + kvn + 32 * 64);

        // this tile's V loads (consumed in phase B)
        bf16x8 VA[2][2];
#pragma unroll
        for (int cf = 0; cf < 2; ++cf)
#pragma unroll
            for (int ks = 0; ks < 2; ++ks)
                VA[cf][ks] = *(const bf16x8*)(vbase + (size_t)cf * 16 * 4096 + kv0 + ks * 32);

        // ---- phase A: swapped QK^T for this wave's 16 q rows ----
        f32x4 S[4];
        {
            const unsigned short(*Kt)[64] = Kl[buf];
            __builtin_amdgcn_s_setprio(1);
#pragma unroll
            for (int cb = 0; cb < 4; ++cb) {
                const int row = cb * 16 + li;
                bf16x8 K0 = *(const bf16x8*)&Kt[row][((g) ^ (row & 7)) * 8];
                bf16x8 K1 = *(const bf16x8*)&Kt[row][((4 + g) ^ (row & 7)) * 8];
                f32x4 s = (f32x4)0.0f;
                s = MFMA16(K0, QA0, s);   // A = K, B = Q  ->  D = S^T
                s = MFMA16(K1, QA1, s);
                S[cb] = s;
            }
            __builtin_amdgcn_s_setprio(0);
        }
        if (j == qt) {  // diagonal tile: mask kv > q
#pragma unroll
            for (int cb = 0; cb < 4; ++cb)
#pragma unroll
                for (int rr = 0; rr < 4; ++rr)
                    if (cb * 16 + 4 * g + rr > qrow) S[cb][rr] = -1e30f;
        }
        // wave-local online softmax (kv lane-local via swapped MFMA)
        f32x4 m4 = S[0];
#pragma unroll
        for (int cb = 1; cb < 4; ++cb)
#pragma unroll
            for (int rr = 0; rr < 4; ++rr) m4[rr] = fmaxf(m4[rr], S[cb][rr]);
        float pm = fmaxf(fmaxf(m4[0], m4[1]), fmaxf(m4[2], m4[3]));
        pm = fmaxf(pm, __shfl_xor(pm, 16));
        pm = fmaxf(pm, __shfl_xor(pm, 32));
        const float mn = fmaxf(m_r, pm);
        const float sc = __expf(m_r - mn);
        m_r = mn;
        float rs = 0.0f;
#pragma unroll
        for (int cb = 0; cb < 4; ++cb) {
            bf16x4 pk;
#pragma unroll
            for (int rr = 0; rr < 4; ++rr) {
                const float pv = __expf(S[cb][rr] - mn);
                rs += pv;
                pk[rr] = (__bf16)pv;
            }
            *(bf16x4*)&Pl[buf][qrow][cb * 16 + 4 * g] = pk;  // ds_write_b64
        }
        rs += __shfl_xor(rs, 16);
        rs += __shfl_xor(rs, 32);
        l_r = l_r * sc + rs;
        if (g == 0) scl[buf][qrow] = sc;

        // land next K tile into the other buffer
        if (havenext) {
            *(ushort8v*)&Kl[buf ^ 1][krow][kslot] = kn0;
            *(ushort8v*)&Kl[buf ^ 1][krow + 32][kslot] = kn1;
        }
        ldsbar();  // the single per-iteration barrier (LDS-only)

        // ---- phase B: PV for this wave's 32 cols, all 64 q rows ----
        __builtin_amdgcn_s_setprio(1);
#pragma unroll
        for (int qb = 0; qb < 4; ++qb) {
            f32x4 scv = *(const f32x4*)&scl[buf][qb * 16 + 4 * g];
            bf16x8 PA0 = *(const bf16x8*)&Pl[buf][qb * 16 + li][8 * g];
            bf16x8 PA1 = *(const bf16x8*)&Pl[buf][qb * 16 + li][32 + 8 * g];
#pragma unroll
            for (int cf = 0; cf < 2; ++cf) {
                f32x4 o = Of[qb][cf];
#pragma unroll
                for (int rr = 0; rr < 4; ++rr) o[rr] *= scv[rr];
                o = MFMA16(PA0, VA[cf][0], o);
                o = MFMA16(PA1, VA[cf][1], o);
                Of[qb][cf] = o;
            }
        }
        __builtin_amdgcn_s_setprio(0);
    }

    if (g == 0) lsum_l[qrow] = l_r;
    ldsbar();

    float* obase = out + (size_t)(b * 4096 + q0 + 4 * g) * 512 + cglob;
#pragma unroll
    for (int qb = 0; qb < 4; ++qb) {
        f32x4 lv = *(const f32x4*)&lsum_l[qb * 16 + 4 * g];
#pragma unroll
        for (int cf = 0; cf < 2; ++cf)
#pragma unroll
            for (int rr = 0; rr < 4; ++rr)
                obase[(size_t)(qb * 16 + rr) * 512 + cf * 16] = Of[qb][cf][rr] / lv[rr];
    }
}

// ---------------------------------------------------------------------------
extern "C" void kernel_launch(void* const* d_in, const int* in_sizes, int n_in,
                              void* d_out, int out_size, void* d_ws, size_t ws_size,
                              hipStream_t stream)
{
    (void)in_sizes; (void)n_in; (void)out_size; (void)ws_size;
    const float* E  = (const float*)d_in[0];
    const float* wq = (const float*)d_in[2];
    const float* bq = (const float*)d_in[3];
    const float* wk = (const float*)d_in[4];
    const float* bk = (const float*)d_in[5];
    const float* wv = (const float*)d_in[6];
    const float* bv = (const float*)d_in[7];

    const size_t qk_elems = (size_t)4 * 4096 * 64;

    unsigned short* Qb = (unsigned short*)d_ws;                 // [4][4096][64] bf16 (x0.125)
    unsigned short* Kb = Qb + qk_elems;                         // [4][4096][64] bf16
    unsigned short* Vt = Kb + qk_elems;                         // [4][512][4096] bf16 (transposed)
    float* out = (float*)d_out;

    proj_kernel<<<dim3(128, 3), 512, 0, stream>>>(E, wq, bq, Qb, wk, bk, Kb, wv, bv, Vt);
    attn_kernel<<<dim3(1024), 256, 0, stream>>>(Qb, Kb, Vt, out);
}